// Round 13
// baseline (91.661 us; speedup 1.0000x reference)
//
#include <hip/hip_runtime.h>
#include <hip/hip_bf16.h>

#define T_DIM 4096
#define C_DIM 1024
#define H_DIM 64
#define B_DIM 4

typedef __attribute__((ext_vector_type(8))) short short8v;
typedef __attribute__((ext_vector_type(4))) float float4v;

__device__ __forceinline__ unsigned short f2bf(float f) {
    __hip_bfloat16 h = __float2bfloat16(f);
    return *reinterpret_cast<unsigned short*>(&h);
}

// pack 8 f32 -> 8 bf16 (packed cvt; element 0 in low half of u32 0)
__device__ __forceinline__ short8v pack8(float4 a, float4 b) {
    short8v r;
    unsigned int* u = (unsigned int*)&r;
    __hip_bfloat162 c0 = __float22bfloat162_rn(make_float2(a.x, a.y));
    __hip_bfloat162 c1 = __float22bfloat162_rn(make_float2(a.z, a.w));
    __hip_bfloat162 c2 = __float22bfloat162_rn(make_float2(b.x, b.y));
    __hip_bfloat162 c3 = __float22bfloat162_rn(make_float2(b.z, b.w));
    u[0] = *(unsigned int*)&c0;
    u[1] = *(unsigned int*)&c1;
    u[2] = *(unsigned int*)&c2;
    u[3] = *(unsigned int*)&c3;
    return r;
}

// permuted position within a 32-row block for V storage (PV frag = one 16B load)
__device__ __forceinline__ int vperm(int t5) {
    return ((t5 & 12) << 1) | (t5 & 3) | ((t5 & 16) >> 2);
}

// tile-prefix P(t) = sum_{t'<t} nchunks(t'), nchunks = 1 + (t>>3)
__device__ __forceinline__ int chunk_prefix(int t) {
    const int g = t >> 3;
    return t + 4 * g * (g - 1) + (t & 7) * g;
}

#define GLL16(gsrc, ldst)                                                         \
    __builtin_amdgcn_global_load_lds(                                             \
        (const __attribute__((address_space(1))) unsigned int*)(gsrc),            \
        (__attribute__((address_space(3))) unsigned int*)(ldst), 16, 0, 0)

// ---------------------------------------------------------------------------
// W prep via LDS transpose (unchanged).
// ---------------------------------------------------------------------------
__global__ __launch_bounds__(256) void wprep(
    const float* __restrict__ Wq, const float* __restrict__ Wk,
    const float* __restrict__ Wv, unsigned short* __restrict__ wt)
{
    __shared__ float tile[64][65];
    const int t  = threadIdx.x;
    const int m  = blockIdx.x >> 4;
    const int k0 = (blockIdx.x & 15) * 64;
    const float* __restrict__ W = (m == 0) ? Wq : (m == 1) ? Wk : Wv;

    const int kr = t >> 4, c4 = (t & 15) * 4;
#pragma unroll
    for (int j = 0; j < 4; ++j) {
        const int row = kr + j * 16;
        const float4 v = *(const float4*)(W + (size_t)(k0 + row) * 64 + c4);
        tile[row][c4 + 0] = v.x; tile[row][c4 + 1] = v.y;
        tile[row][c4 + 2] = v.z; tile[row][c4 + 3] = v.w;
    }
    __syncthreads();

    const int col = t >> 2, q = t & 3;
    short8v s0, s1;
#pragma unroll
    for (int j = 0; j < 8; ++j) s0[j] = (short)f2bf(tile[q * 16 + j][col]);
#pragma unroll
    for (int j = 0; j < 8; ++j) s1[j] = (short)f2bf(tile[q * 16 + 8 + j][col]);
    unsigned short* dst = wt + (size_t)(m * 64 + col) * 1024 + k0 + q * 16;
    *(short8v*)dst = s0;
    *(short8v*)(dst + 8) = s1;
}

// ---------------------------------------------------------------------------
// QKV projection v3: BARRIER-FREE streaming GEMM. Block = 32 rows, 512 thr =
// 8 waves = (2 col-halves of 96) x (4 K-quarters of 256). Each wave streams
// its K-quarter with DIRECT global loads (A: x rows f32->bf16 converted once;
// B: wt cols, L2-hot, 16-lane x 64B coalesced) — no LDS staging, no barriers,
// ~30 loads in flight per wave. Single end-of-kernel 4-way K-combine via LDS.
// q pre-scaled by C^-0.5*log2(e); v stored h-major with vperm'd t.
// ---------------------------------------------------------------------------
__global__ __launch_bounds__(512, 4) void qkv_gemm(
    const float* __restrict__ x, const unsigned short* __restrict__ wt,
    const float* __restrict__ bq, const float* __restrict__ bk,
    const float* __restrict__ bv,
    unsigned short* __restrict__ qb, unsigned short* __restrict__ kmat,
    unsigned short* __restrict__ vP)
{
    __shared__ float comm[6][64][48];   // 72 KB, used only at the end

    const int t    = threadIdx.x;
    const int lane = t & 63;
    const int w    = t >> 6;
    const int l15  = lane & 15;
    const int g4   = lane >> 4;
    const int r0   = blockIdx.x * 32;

    const int cgr = w & 1;      // col half (0: cols 0-95, 1: cols 96-191)
    const int kq  = w >> 1;     // K-quarter (256 wide)

    const float* __restrict__ xr0 =
        x + (size_t)(r0 + l15) * C_DIM + kq * 256 + 8 * g4;
    const float* __restrict__ xr1 = xr0 + 16 * C_DIM;
    const unsigned short* __restrict__ wb =
        wt + kq * 256 + 8 * g4;   // + col*1024 + kb*32

    float4v acc[2][6];
#pragma unroll
    for (int rgi = 0; rgi < 2; ++rgi)
#pragma unroll
        for (int cg = 0; cg < 6; ++cg) acc[rgi][cg] = (float4v){0.f, 0.f, 0.f, 0.f};

#pragma unroll
    for (int kb = 0; kb < 8; ++kb) {
        const float4 a00 = *(const float4*)(xr0 + kb * 32);
        const float4 a01 = *(const float4*)(xr0 + kb * 32 + 4);
        const float4 a10 = *(const float4*)(xr1 + kb * 32);
        const float4 a11 = *(const float4*)(xr1 + kb * 32 + 4);
        const short8v af0 = pack8(a00, a01);
        const short8v af1 = pack8(a10, a11);
#pragma unroll
        for (int cg = 0; cg < 6; ++cg) {
            const short8v bf = *(const short8v*)(
                wb + (size_t)(cgr * 96 + cg * 16 + l15) * 1024 + kb * 32);
            acc[0][cg] = __builtin_amdgcn_mfma_f32_16x16x32_bf16(af0, bf, acc[0][cg], 0, 0, 0);
            acc[1][cg] = __builtin_amdgcn_mfma_f32_16x16x32_bf16(af1, bf, acc[1][cg], 0, 0, 0);
        }
    }

    // 4-way K-combine: kq>0 waves write, one barrier, kq==0 waves reduce+store
    if (kq > 0) {
        float* c = &comm[w - 2][lane][0];
#pragma unroll
        for (int rgi = 0; rgi < 2; ++rgi)
#pragma unroll
            for (int cg = 0; cg < 6; ++cg)
#pragma unroll
                for (int e = 0; e < 4; ++e)
                    c[(rgi * 6 + cg) * 4 + e] = acc[rgi][cg][e];
    }
    __syncthreads();
    if (kq == 0) {
#pragma unroll
        for (int j = 0; j < 3; ++j) {
            const float* c = &comm[j * 2 + cgr][lane][0];
#pragma unroll
            for (int rgi = 0; rgi < 2; ++rgi)
#pragma unroll
                for (int cg = 0; cg < 6; ++cg)
#pragma unroll
                    for (int e = 0; e < 4; ++e)
                        acc[rgi][cg][e] += c[(rgi * 6 + cg) * 4 + e];
        }

        const float qs = 0.03125f * 1.44269504088896f;  // C^-0.5 * log2(e)
#pragma unroll
        for (int rgi = 0; rgi < 2; ++rgi) {
#pragma unroll
            for (int cg = 0; cg < 6; ++cg) {
                const int cabs = cgr * 96 + cg * 16 + l15;
                const int m    = cabs >> 6;
                const int h    = cabs & 63;
                const float bb = ((m == 0) ? bq : (m == 1) ? bk : bv)[h];
#pragma unroll
                for (int rr = 0; rr < 4; ++rr) {
                    const int row = r0 + rgi * 16 + 4 * g4 + rr;
                    const float vv = acc[rgi][cg][rr] + bb;
                    if (m == 0) {
                        qb[(size_t)row * 64 + h] = f2bf(vv * qs);
                    } else if (m == 1) {
                        kmat[(size_t)row * 64 + h] = f2bf(vv);
                    } else {
                        const int b_i = row >> 12;
                        const int tt  = row & 4095;
                        const int tp  = (tt & ~31) | vperm(tt & 31);
                        vP[((size_t)b_i * 64 + h) * T_DIM + tp] = f2bf(vv);
                    }
                }
            }
        }
    }
}

// ---------------------------------------------------------------------------
// Attention phase 1 (unchanged from r12). Block = (batch, 64-row q tile,
// 512-kv chunk), grid 1152, 256 thr = 4 waves; triple-buffered LDS staging.
// ---------------------------------------------------------------------------
__global__ __launch_bounds__(256, 4) void attn_part(
    const unsigned short* __restrict__ qb, const unsigned short* __restrict__ kmat,
    const unsigned short* __restrict__ vP, float* __restrict__ pO,
    float* __restrict__ pl)
{
    __shared__ __align__(16) unsigned char lk[3][4096];   // 32 kv x 128B
    __shared__ __align__(16) unsigned char lv[3][4096];   // 64 h  x 64B

    const int tid  = threadIdx.x;
    const int w    = tid >> 6;           // 0..3
    const int lane = tid & 63;
    const int l15  = lane & 15;
    const int g    = lane >> 4;

    const int b   = blockIdx.x & 3;
    const int idx = 287 - (blockIdx.x >> 2);   // longest chunks first
    int t = 0;
    for (int tt = 1; tt < 64; ++tt)
        if (chunk_prefix(tt) <= idx) t = tt;
    const int c    = idx - chunk_prefix(t);
    const int q0   = t * 64;
    const int kv_l = q0 + 64;
    const int d0   = c * 512;
    const int dend = (d0 + 512 < kv_l) ? (d0 + 512) : kv_l;
    const int ns   = (dend - d0) >> 5;         // 2..16 steps
    const int slot = b * 288 + idx;

    const unsigned char* kB = (const unsigned char*)kmat + (size_t)b * T_DIM * 128;
    const unsigned char* vB = (const unsigned char*)vP + (size_t)b * 64 * T_DIM * 2;
    const int krow = tid >> 3, kdg = tid & 7;
    const int vh = tid >> 2, vdg = tid & 3;
    const unsigned char* ksrc = kB + krow * 128 + ((kdg ^ (krow & 7)) * 16);
    const unsigned char* vsrc = vB + (size_t)vh * 8192 + ((vdg ^ (vh & 3)) * 16);
    const int kdst = tid * 16;

#define STAGE(p, ss)                                                          \
    {                                                                         \
        const int off_ = d0 + (ss) * 32;                                      \
        GLL16(ksrc + (size_t)off_ * 128, &lk[p][kdst]);                       \
        GLL16(vsrc + (size_t)off_ * 2,   &lv[p][kdst]);                       \
    }

    const unsigned short* qrow = qb + ((size_t)b * T_DIM + q0 + 16 * w + l15) * 64;
    const short8v qf0 = *(const short8v*)(qrow + 8 * g);
    const short8v qf1 = *(const short8v*)(qrow + 32 + 8 * g);

    short8v kones;
#pragma unroll
    for (int j = 0; j < 8; ++j) kones[j] = (short)0x3F80;

    float4v acc[4];
    float4v accl = (float4v){0.f, 0.f, 0.f, 0.f};
#pragma unroll
    for (int f = 0; f < 4; ++f) acc[f] = (float4v){0.f, 0.f, 0.f, 0.f};

    const int qmax = q0 + 16 * w + 15;
    const int kxor = l15 & 7;
    const int vxor = l15 & 3;

    STAGE(0, 0);
    STAGE(1, (ns > 1) ? 1 : 0);
    asm volatile("s_waitcnt vmcnt(2)" ::: "memory");
    __builtin_amdgcn_s_barrier();

    int p = 0;
    for (int s = 0; s < ns; ++s) {
        const int ps = (p + 2 >= 3) ? (p - 1) : (p + 2);
        const int sn = (s + 2 < ns) ? (s + 2) : (ns - 1);
        STAGE(ps, sn);

        const int kv0 = d0 + s * 32;
        if (kv0 <= qmax) {
            const short8v ka0 = *(const short8v*)&lk[p][(l15 * 8 + (g ^ kxor)) * 16];
            const short8v ka1 = *(const short8v*)&lk[p][(l15 * 8 + ((4 + g) ^ kxor)) * 16];
            const short8v ka2 = *(const short8v*)&lk[p][((16 + l15) * 8 + (g ^ kxor)) * 16];
            const short8v ka3 = *(const short8v*)&lk[p][((16 + l15) * 8 + ((4 + g) ^ kxor)) * 16];
            short8v vb[4];
#pragma unroll
            for (int f = 0; f < 4; ++f)
                vb[f] = *(const short8v*)&lv[p][((f * 16 + l15) * 4 + (g ^ vxor)) * 16];

            const float4v z = (float4v){0.f, 0.f, 0.f, 0.f};
            float4v slo = __builtin_amdgcn_mfma_f32_16x16x32_bf16(ka0, qf0, z, 0, 0, 0);
            slo = __builtin_amdgcn_mfma_f32_16x16x32_bf16(ka1, qf1, slo, 0, 0, 0);
            float4v shi = __builtin_amdgcn_mfma_f32_16x16x32_bf16(ka2, qf0, z, 0, 0, 0);
            shi = __builtin_amdgcn_mfma_f32_16x16x32_bf16(ka3, qf1, shi, 0, 0, 0);

            float pl_[4], ph_[4];
            if (kv0 + 31 <= q0 + 16 * w) {      // fully below diagonal
#pragma unroll
                for (int r = 0; r < 4; ++r) {
                    pl_[r] = exp2f(slo[r]);
                    ph_[r] = exp2f(shi[r]);
                }
            } else {
                const int qabs = q0 + 16 * w + l15;
#pragma unroll
                for (int r = 0; r < 4; ++r) {
                    const int kvlo = kv0 + 4 * g + r;
                    pl_[r] = (kvlo <= qabs) ? exp2f(slo[r]) : 0.f;
                    ph_[r] = (kvlo + 16 <= qabs) ? exp2f(shi[r]) : 0.f;
                }
            }
            short8v pa;
            {
                unsigned int* pu = (unsigned int*)&pa;
                __hip_bfloat162 c0 = __float22bfloat162_rn(make_float2(pl_[0], pl_[1]));
                __hip_bfloat162 c1 = __float22bfloat162_rn(make_float2(pl_[2], pl_[3]));
                __hip_bfloat162 c2 = __float22bfloat162_rn(make_float2(ph_[0], ph_[1]));
                __hip_bfloat162 c3 = __float22bfloat162_rn(make_float2(ph_[2], ph_[3]));
                pu[0] = *(unsigned int*)&c0;
                pu[1] = *(unsigned int*)&c1;
                pu[2] = *(unsigned int*)&c2;
                pu[3] = *(unsigned int*)&c3;
            }
#pragma unroll
            for (int f = 0; f < 4; ++f)
                acc[f] = __builtin_amdgcn_mfma_f32_16x16x32_bf16(pa, vb[f], acc[f], 0, 0, 0);
            accl = __builtin_amdgcn_mfma_f32_16x16x32_bf16(pa, kones, accl, 0, 0, 0);
        }

        asm volatile("s_waitcnt vmcnt(2) lgkmcnt(0)" ::: "memory");
        __builtin_amdgcn_s_barrier();
        p = (p + 1 >= 3) ? 0 : (p + 1);
    }

    // epilogue: acc[f][r] = O[q = 16w+4g+r][h = f*16+l15]
    float* po = pO + (size_t)slot * 4096 + (size_t)(16 * w) * 64;
#pragma unroll
    for (int f = 0; f < 4; ++f)
#pragma unroll
        for (int r = 0; r < 4; ++r)
            po[(4 * g + r) * 64 + f * 16 + l15] = acc[f][r];
    if (l15 == 0) {
#pragma unroll
        for (int r = 0; r < 4; ++r)
            pl[(size_t)slot * 64 + 16 * w + 4 * g + r] = accl[r];
    }
#undef STAGE
}

// ---------------------------------------------------------------------------
// Attention phase 2 (unchanged from r12): out = (sum_c pO) / (sum_c l).
// ---------------------------------------------------------------------------
__global__ __launch_bounds__(256) void attn_comb(
    const float* __restrict__ pO, const float* __restrict__ pl,
    float* __restrict__ out)
{
    const int tid  = blockIdx.x * 256 + threadIdx.x;  // 0..262143
    const int row  = tid >> 4;
    const int h4   = (tid & 15) * 4;
    const int b    = row >> 12;
    const int brow = row & 4095;
    const int t    = brow >> 6;
    const int rr   = brow & 63;
    const int nc   = 1 + (t >> 3);
    const int base = b * 288 + chunk_prefix(t);

    const float* src  = pO + (size_t)base * 4096 + rr * 64 + h4;
    const float* lsrc = pl + (size_t)base * 64 + rr;
    float4 o = make_float4(0.f, 0.f, 0.f, 0.f);
    float l = 0.f;
    for (int c = 0; c < nc; ++c) {
        const float4 s = *(const float4*)(src + (size_t)c * 4096);
        o.x += s.x; o.y += s.y; o.z += s.z; o.w += s.w;
        l += lsrc[(size_t)c * 64];
    }
    const float inv = 1.f / l;
    o.x *= inv; o.y *= inv; o.z *= inv; o.w *= inv;
    *(float4*)(out + (size_t)row * 64 + h4) = o;
}

extern "C" void kernel_launch(void* const* d_in, const int* in_sizes, int n_in,
                              void* d_out, int out_size, void* d_ws, size_t ws_size,
                              hipStream_t stream) {
    const float* x  = (const float*)d_in[0];
    const float* Wq = (const float*)d_in[1];
    const float* bq = (const float*)d_in[2];
    const float* Wk = (const float*)d_in[3];
    const float* bk = (const float*)d_in[4];
    const float* Wv = (const float*)d_in[5];
    const float* bv = (const float*)d_in[6];
    float* out = (float*)d_out;

    char* ws = (char*)d_ws;
    unsigned short* qb   = (unsigned short*)(ws);                    // 2 MB
    unsigned short* kmat = (unsigned short*)(ws + (2u << 20));       // 2 MB
    unsigned short* vP   = (unsigned short*)(ws + (4u << 20));       // 2 MB
    unsigned short* wt   = (unsigned short*)(ws + (6u << 20));       // 384 KB
    float*          pO   = (float*)(ws + (8u << 20));                // 18.9 MB
    float*          pl   = (float*)(ws + (8u << 20) + 18874368u);    // 295 KB

    wprep<<<48, 256, 0, stream>>>(Wq, Wk, Wv, wt);
    qkv_gemm<<<512, 512, 0, stream>>>(x, wt, bq, bk, bv, qb, kmat, vP);
    attn_part<<<1152, 256, 0, stream>>>(qb, kmat, vP, pO, pl);
    attn_comb<<<1024, 256, 0, stream>>>(pO, pl, out);
}

// Round 14
// 55.201 us; speedup vs baseline: 1.6605x; 1.6605x over previous
//
#include <hip/hip_runtime.h>
#include <hip/hip_bf16.h>

#define T_DIM 4096
#define C_DIM 1024
#define H_DIM 64
#define B_DIM 4

typedef __attribute__((ext_vector_type(8))) short short8v;
typedef __attribute__((ext_vector_type(4))) short short4v;
typedef __attribute__((ext_vector_type(4))) float float4v;

__device__ __forceinline__ unsigned short f2bf(float f) {
    __hip_bfloat16 h = __float2bfloat16(f);
    return *reinterpret_cast<unsigned short*>(&h);
}
__device__ __forceinline__ float bf2f(unsigned short u) {
    __hip_bfloat16 h = *reinterpret_cast<__hip_bfloat16*>(&u);
    return __bfloat162float(h);
}

// permuted position within a 32-row block for V storage (PV frag = one 16B load)
__device__ __forceinline__ int vperm(int t5) {
    return ((t5 & 12) << 1) | (t5 & 3) | ((t5 & 16) >> 2);
}

// tile-prefix P(t) = sum_{t'<t} nchunks(t'), nchunks = 1 + (t>>3)
__device__ __forceinline__ int chunk_prefix(int t) {
    const int g = t >> 3;
    return t + 4 * g * (g - 1) + (t & 7) * g;
}

#define GLL16(gsrc, ldst)                                                         \
    __builtin_amdgcn_global_load_lds(                                             \
        (const __attribute__((address_space(1))) unsigned int*)(gsrc),            \
        (__attribute__((address_space(3))) unsigned int*)(ldst), 16, 0, 0)

// ---------------------------------------------------------------------------
// W prep via LDS transpose (unchanged).
// ---------------------------------------------------------------------------
__global__ __launch_bounds__(256) void wprep(
    const float* __restrict__ Wq, const float* __restrict__ Wk,
    const float* __restrict__ Wv, unsigned short* __restrict__ wt)
{
    __shared__ float tile[64][65];
    const int t  = threadIdx.x;
    const int m  = blockIdx.x >> 4;
    const int k0 = (blockIdx.x & 15) * 64;
    const float* __restrict__ W = (m == 0) ? Wq : (m == 1) ? Wk : Wv;

    const int kr = t >> 4, c4 = (t & 15) * 4;
#pragma unroll
    for (int j = 0; j < 4; ++j) {
        const int row = kr + j * 16;
        const float4 v = *(const float4*)(W + (size_t)(k0 + row) * 64 + c4);
        tile[row][c4 + 0] = v.x; tile[row][c4 + 1] = v.y;
        tile[row][c4 + 2] = v.z; tile[row][c4 + 3] = v.w;
    }
    __syncthreads();

    const int col = t >> 2, q = t & 3;
    short8v s0, s1;
#pragma unroll
    for (int j = 0; j < 8; ++j) s0[j] = (short)f2bf(tile[q * 16 + j][col]);
#pragma unroll
    for (int j = 0; j < 8; ++j) s1[j] = (short)f2bf(tile[q * 16 + 8 + j][col]);
    unsigned short* dst = wt + (size_t)(m * 64 + col) * 1024 + k0 + q * 16;
    *(short8v*)dst = s0;
    *(short8v*)(dst + 8) = s1;
}

// ---------------------------------------------------------------------------
// QKV projection (REVERTED to the r12-verified staged version: r13's
// barrier-free variant spilled ~28MB of scratch and ran 2.4x slower).
// LDS GEMM, 16x16x32 MFMA, BM=32, grid 512 (2 blocks/CU); triple-buffered wt
// staging with counted vmcnt(4); x reg-staged bf16 depth-2.
// ---------------------------------------------------------------------------
__global__ __launch_bounds__(512, 2) void qkv_gemm(
    const float* __restrict__ x, const unsigned short* __restrict__ wt,
    const float* __restrict__ bq, const float* __restrict__ bk,
    const float* __restrict__ bv,
    unsigned short* __restrict__ qb, unsigned short* __restrict__ kmat,
    unsigned short* __restrict__ vP)
{
    __shared__ __align__(16) unsigned char lx[2][4096];    // 32 rows x 128B bf16
    __shared__ __align__(16) unsigned char lw[3][24576];   // 192 cols x 128B bf16

    const int t    = threadIdx.x;
    const int lane = t & 63;
    const int w    = t >> 6;
    const int l15  = lane & 15;
    const int g4   = lane >> 4;
    const int r0   = blockIdx.x * 32;

    const int rg  = w & 1;
    const int cgr = (w >> 1) & 1;
    const int kh  = w >> 2;

    const int srow  = t >> 4;            // 0..31
    const int sq    = t & 15;            // 16B f32 chunks
    const int xbyte = srow * 128 + ((sq >> 1) ^ (srow & 7)) * 16 + (sq & 1) * 8;
    const float* __restrict__ xsrc = x + (size_t)(r0 + srow) * C_DIM + sq * 4;
    const int wgs = (t & 7) ^ ((t >> 3) & 7);
    const unsigned char* __restrict__ wB = (const unsigned char*)wt;

    float4v acc[6];
#pragma unroll
    for (int cg = 0; cg < 6; ++cg) acc[cg] = (float4v){0.f, 0.f, 0.f, 0.f};

#define WSTAGE(p, kb)                                                             \
    {                                                                             \
        _Pragma("unroll")                                                         \
        for (int i = 0; i < 3; ++i)                                               \
            GLL16(wB + (size_t)(i * 64 + (t >> 3)) * 2048 + (kb) * 128 + wgs * 16,\
                  &lw[p][(i * 512 + t) * 16]);                                    \
    }
#define XCVT_WRITE(p, v)                                                          \
    {                                                                             \
        __hip_bfloat162 c0_ = __float22bfloat162_rn(make_float2((v).x, (v).y));   \
        __hip_bfloat162 c1_ = __float22bfloat162_rn(make_float2((v).z, (v).w));   \
        unsigned int* d_ = (unsigned int*)&lx[p][xbyte];                          \
        d_[0] = *(unsigned int*)&c0_;                                             \
        d_[1] = *(unsigned int*)&c1_;                                             \
    }

    float4 xvA, xvB;

    {
        const float4 x0 = *(const float4*)xsrc;
        WSTAGE(0, 0);
        WSTAGE(1, 1);
        __builtin_amdgcn_sched_barrier(0);
        xvA = *(const float4*)(xsrc + 64);
        XCVT_WRITE(0, x0);
        asm volatile("s_waitcnt vmcnt(4) lgkmcnt(0)" ::: "memory");
        __builtin_amdgcn_s_barrier();
        __builtin_amdgcn_sched_barrier(0);
    }

    const int arow = rg * 16 + l15;
    const int axor = arow & 7;
    const int kg   = kh * 4 + g4;

#pragma unroll
    for (int kb = 0; kb < 14; ++kb) {
        const int p  = kb % 3;
        const int ps = (kb + 2) % 3;
        WSTAGE(ps, kb + 2);
        __builtin_amdgcn_sched_barrier(0);
        if ((kb & 1) == 0) xvB = *(const float4*)(xsrc + (kb + 2) * 64);
        else               xvA = *(const float4*)(xsrc + (kb + 2) * 64);

        const short8v af = *(const short8v*)&lx[kb & 1][arow * 128 + (kg ^ axor) * 16];
#pragma unroll
        for (int cg = 0; cg < 6; ++cg) {
            const int col = cgr * 96 + cg * 16 + l15;
            const short8v bf =
                *(const short8v*)&lw[p][col * 128 + ((kg ^ (col & 7))) * 16];
            acc[cg] = __builtin_amdgcn_mfma_f32_16x16x32_bf16(af, bf, acc[cg], 0, 0, 0);
        }

        if ((kb & 1) == 0) { XCVT_WRITE((kb + 1) & 1, xvA); }
        else               { XCVT_WRITE((kb + 1) & 1, xvB); }

        asm volatile("s_waitcnt vmcnt(4) lgkmcnt(0)" ::: "memory");
        __builtin_amdgcn_s_barrier();
        __builtin_amdgcn_sched_barrier(0);
    }
    {
        const short8v af = *(const short8v*)&lx[0][arow * 128 + (kg ^ axor) * 16];
#pragma unroll
        for (int cg = 0; cg < 6; ++cg) {
            const int col = cgr * 96 + cg * 16 + l15;
            const short8v bf =
                *(const short8v*)&lw[2][col * 128 + ((kg ^ (col & 7))) * 16];
            acc[cg] = __builtin_amdgcn_mfma_f32_16x16x32_bf16(af, bf, acc[cg], 0, 0, 0);
        }
        XCVT_WRITE(1, xvA);
        asm volatile("s_waitcnt vmcnt(0) lgkmcnt(0)" ::: "memory");
        __builtin_amdgcn_s_barrier();
        __builtin_amdgcn_sched_barrier(0);
    }
    {
        const short8v af = *(const short8v*)&lx[1][arow * 128 + (kg ^ axor) * 16];
#pragma unroll
        for (int cg = 0; cg < 6; ++cg) {
            const int col = cgr * 96 + cg * 16 + l15;
            const short8v bf =
                *(const short8v*)&lw[0][col * 128 + ((kg ^ (col & 7))) * 16];
            acc[cg] = __builtin_amdgcn_mfma_f32_16x16x32_bf16(af, bf, acc[cg], 0, 0, 0);
        }
    }
    __syncthreads();

    float* comm = (float*)lw;
    if (kh == 1) {
        const int base = ((w - 4) * 64 + lane) * 24;
#pragma unroll
        for (int cg = 0; cg < 6; ++cg)
#pragma unroll
            for (int e = 0; e < 4; ++e) comm[base + cg * 4 + e] = acc[cg][e];
    }
    __syncthreads();
    if (kh == 0) {
        const int base = (w * 64 + lane) * 24;
#pragma unroll
        for (int cg = 0; cg < 6; ++cg)
#pragma unroll
            for (int e = 0; e < 4; ++e) acc[cg][e] += comm[base + cg * 4 + e];

        const float qs = 0.03125f * 1.44269504088896f;  // C^-0.5 * log2(e)
#pragma unroll
        for (int cg = 0; cg < 6; ++cg) {
            const int cabs = cgr * 96 + cg * 16 + l15;
            const int m    = cabs >> 6;
            const int h    = cabs & 63;
            const float bb = ((m == 0) ? bq : (m == 1) ? bk : bv)[h];
#pragma unroll
            for (int rr = 0; rr < 4; ++rr) {
                const int row = r0 + rg * 16 + 4 * g4 + rr;
                const float vv = acc[cg][rr] + bb;
                if (m == 0) {
                    qb[(size_t)row * 64 + h] = f2bf(vv * qs);
                } else if (m == 1) {
                    kmat[(size_t)row * 64 + h] = f2bf(vv);
                } else {
                    const int b_i = row >> 12;
                    const int tt  = row & 4095;
                    const int tp  = (tt & ~31) | vperm(tt & 31);
                    vP[((size_t)b_i * 64 + h) * T_DIM + tp] = f2bf(vv);
                }
            }
        }
    }
#undef WSTAGE
#undef XCVT_WRITE
}

// ---------------------------------------------------------------------------
// Attention phase 1 (r12 structure; pO now written as bf16 — halves the
// partial-O HBM traffic; l stays f32). Block = (batch, 64-row q tile,
// 512-kv chunk), grid 1152, 256 thr = 4 waves; triple-buffered LDS staging.
// ---------------------------------------------------------------------------
__global__ __launch_bounds__(256, 4) void attn_part(
    const unsigned short* __restrict__ qb, const unsigned short* __restrict__ kmat,
    const unsigned short* __restrict__ vP, unsigned short* __restrict__ pO,
    float* __restrict__ pl)
{
    __shared__ __align__(16) unsigned char lk[3][4096];   // 32 kv x 128B
    __shared__ __align__(16) unsigned char lv[3][4096];   // 64 h  x 64B

    const int tid  = threadIdx.x;
    const int w    = tid >> 6;           // 0..3
    const int lane = tid & 63;
    const int l15  = lane & 15;
    const int g    = lane >> 4;

    const int b   = blockIdx.x & 3;
    const int idx = 287 - (blockIdx.x >> 2);   // longest chunks first
    int t = 0;
    for (int tt = 1; tt < 64; ++tt)
        if (chunk_prefix(tt) <= idx) t = tt;
    const int c    = idx - chunk_prefix(t);
    const int q0   = t * 64;
    const int kv_l = q0 + 64;
    const int d0   = c * 512;
    const int dend = (d0 + 512 < kv_l) ? (d0 + 512) : kv_l;
    const int ns   = (dend - d0) >> 5;         // 2..16 steps
    const int slot = b * 288 + idx;

    const unsigned char* kB = (const unsigned char*)kmat + (size_t)b * T_DIM * 128;
    const unsigned char* vB = (const unsigned char*)vP + (size_t)b * 64 * T_DIM * 2;
    const int krow = tid >> 3, kdg = tid & 7;
    const int vh = tid >> 2, vdg = tid & 3;
    const unsigned char* ksrc = kB + krow * 128 + ((kdg ^ (krow & 7)) * 16);
    const unsigned char* vsrc = vB + (size_t)vh * 8192 + ((vdg ^ (vh & 3)) * 16);
    const int kdst = tid * 16;

#define STAGE(p, ss)                                                          \
    {                                                                         \
        const int off_ = d0 + (ss) * 32;                                      \
        GLL16(ksrc + (size_t)off_ * 128, &lk[p][kdst]);                       \
        GLL16(vsrc + (size_t)off_ * 2,   &lv[p][kdst]);                       \
    }

    const unsigned short* qrow = qb + ((size_t)b * T_DIM + q0 + 16 * w + l15) * 64;
    const short8v qf0 = *(const short8v*)(qrow + 8 * g);
    const short8v qf1 = *(const short8v*)(qrow + 32 + 8 * g);

    short8v kones;
#pragma unroll
    for (int j = 0; j < 8; ++j) kones[j] = (short)0x3F80;

    float4v acc[4];
    float4v accl = (float4v){0.f, 0.f, 0.f, 0.f};
#pragma unroll
    for (int f = 0; f < 4; ++f) acc[f] = (float4v){0.f, 0.f, 0.f, 0.f};

    const int qmax = q0 + 16 * w + 15;
    const int kxor = l15 & 7;
    const int vxor = l15 & 3;

    STAGE(0, 0);
    STAGE(1, (ns > 1) ? 1 : 0);
    asm volatile("s_waitcnt vmcnt(2)" ::: "memory");
    __builtin_amdgcn_s_barrier();

    int p = 0;
    for (int s = 0; s < ns; ++s) {
        const int ps = (p + 2 >= 3) ? (p - 1) : (p + 2);
        const int sn = (s + 2 < ns) ? (s + 2) : (ns - 1);
        STAGE(ps, sn);

        const int kv0 = d0 + s * 32;
        if (kv0 <= qmax) {
            const short8v ka0 = *(const short8v*)&lk[p][(l15 * 8 + (g ^ kxor)) * 16];
            const short8v ka1 = *(const short8v*)&lk[p][(l15 * 8 + ((4 + g) ^ kxor)) * 16];
            const short8v ka2 = *(const short8v*)&lk[p][((16 + l15) * 8 + (g ^ kxor)) * 16];
            const short8v ka3 = *(const short8v*)&lk[p][((16 + l15) * 8 + ((4 + g) ^ kxor)) * 16];
            short8v vb[4];
#pragma unroll
            for (int f = 0; f < 4; ++f)
                vb[f] = *(const short8v*)&lv[p][((f * 16 + l15) * 4 + (g ^ vxor)) * 16];

            const float4v z = (float4v){0.f, 0.f, 0.f, 0.f};
            float4v slo = __builtin_amdgcn_mfma_f32_16x16x32_bf16(ka0, qf0, z, 0, 0, 0);
            slo = __builtin_amdgcn_mfma_f32_16x16x32_bf16(ka1, qf1, slo, 0, 0, 0);
            float4v shi = __builtin_amdgcn_mfma_f32_16x16x32_bf16(ka2, qf0, z, 0, 0, 0);
            shi = __builtin_amdgcn_mfma_f32_16x16x32_bf16(ka3, qf1, shi, 0, 0, 0);

            float pl_[4], ph_[4];
            if (kv0 + 31 <= q0 + 16 * w) {      // fully below diagonal
#pragma unroll
                for (int r = 0; r < 4; ++r) {
                    pl_[r] = exp2f(slo[r]);
                    ph_[r] = exp2f(shi[r]);
                }
            } else {
                const int qabs = q0 + 16 * w + l15;
#pragma unroll
                for (int r = 0; r < 4; ++r) {
                    const int kvlo = kv0 + 4 * g + r;
                    pl_[r] = (kvlo <= qabs) ? exp2f(slo[r]) : 0.f;
                    ph_[r] = (kvlo + 16 <= qabs) ? exp2f(shi[r]) : 0.f;
                }
            }
            short8v pa;
            {
                unsigned int* pu = (unsigned int*)&pa;
                __hip_bfloat162 c0 = __float22bfloat162_rn(make_float2(pl_[0], pl_[1]));
                __hip_bfloat162 c1 = __float22bfloat162_rn(make_float2(pl_[2], pl_[3]));
                __hip_bfloat162 c2 = __float22bfloat162_rn(make_float2(ph_[0], ph_[1]));
                __hip_bfloat162 c3 = __float22bfloat162_rn(make_float2(ph_[2], ph_[3]));
                pu[0] = *(unsigned int*)&c0;
                pu[1] = *(unsigned int*)&c1;
                pu[2] = *(unsigned int*)&c2;
                pu[3] = *(unsigned int*)&c3;
            }
#pragma unroll
            for (int f = 0; f < 4; ++f)
                acc[f] = __builtin_amdgcn_mfma_f32_16x16x32_bf16(pa, vb[f], acc[f], 0, 0, 0);
            accl = __builtin_amdgcn_mfma_f32_16x16x32_bf16(pa, kones, accl, 0, 0, 0);
        }

        asm volatile("s_waitcnt vmcnt(2) lgkmcnt(0)" ::: "memory");
        __builtin_amdgcn_s_barrier();
        p = (p + 1 >= 3) ? 0 : (p + 1);
    }

    // epilogue: acc[f][r] = O[q = 16w+4g+r][h = f*16+l15], stored bf16
    unsigned short* po = pO + (size_t)slot * 4096 + (size_t)(16 * w) * 64;
#pragma unroll
    for (int f = 0; f < 4; ++f)
#pragma unroll
        for (int r = 0; r < 4; ++r)
            po[(4 * g + r) * 64 + f * 16 + l15] = f2bf(acc[f][r]);
    if (l15 == 0) {
#pragma unroll
        for (int r = 0; r < 4; ++r)
            pl[(size_t)slot * 64 + 16 * w + 4 * g + r] = accl[r];
    }
#undef STAGE
}

// ---------------------------------------------------------------------------
// Attention phase 2: out = (sum_c bf16(pO)) / (sum_c l). thread = (row, 4 h).
// ---------------------------------------------------------------------------
__global__ __launch_bounds__(256) void attn_comb(
    const unsigned short* __restrict__ pO, const float* __restrict__ pl,
    float* __restrict__ out)
{
    const int tid  = blockIdx.x * 256 + threadIdx.x;  // 0..262143
    const int row  = tid >> 4;
    const int h4   = (tid & 15) * 4;
    const int b    = row >> 12;
    const int brow = row & 4095;
    const int t    = brow >> 6;
    const int rr   = brow & 63;
    const int nc   = 1 + (t >> 3);
    const int base = b * 288 + chunk_prefix(t);

    const unsigned short* src = pO + (size_t)base * 4096 + rr * 64 + h4;
    const float* lsrc = pl + (size_t)base * 64 + rr;
    float4 o = make_float4(0.f, 0.f, 0.f, 0.f);
    float l = 0.f;
    for (int c = 0; c < nc; ++c) {
        const short4v s = *(const short4v*)(src + (size_t)c * 4096);
        o.x += bf2f((unsigned short)s[0]);
        o.y += bf2f((unsigned short)s[1]);
        o.z += bf2f((unsigned short)s[2]);
        o.w += bf2f((unsigned short)s[3]);
        l += lsrc[(size_t)c * 64];
    }
    const float inv = 1.f / l;
    o.x *= inv; o.y *= inv; o.z *= inv; o.w *= inv;
    *(float4*)(out + (size_t)row * 64 + h4) = o;
}

extern "C" void kernel_launch(void* const* d_in, const int* in_sizes, int n_in,
                              void* d_out, int out_size, void* d_ws, size_t ws_size,
                              hipStream_t stream) {
    const float* x  = (const float*)d_in[0];
    const float* Wq = (const float*)d_in[1];
    const float* bq = (const float*)d_in[2];
    const float* Wk = (const float*)d_in[3];
    const float* bk = (const float*)d_in[4];
    const float* Wv = (const float*)d_in[5];
    const float* bv = (const float*)d_in[6];
    float* out = (float*)d_out;

    char* ws = (char*)d_ws;
    unsigned short* qb   = (unsigned short*)(ws);                    // 2 MB
    unsigned short* kmat = (unsigned short*)(ws + (2u << 20));       // 2 MB
    unsigned short* vP   = (unsigned short*)(ws + (4u << 20));       // 2 MB
    unsigned short* wt   = (unsigned short*)(ws + (6u << 20));       // 384 KB
    unsigned short* pO   = (unsigned short*)(ws + (8u << 20));       // 9.44 MB (bf16)
    float*          pl   = (float*)(ws + (8u << 20) + 9437184u);     // 295 KB

    wprep<<<48, 256, 0, stream>>>(Wq, Wk, Wv, wt);
    qkv_gemm<<<512, 512, 0, stream>>>(x, wt, bq, bk, bv, qb, kmat, vP);
    attn_part<<<1152, 256, 0, stream>>>(qb, kmat, vP, pO, pl);
    attn_comb<<<1024, 256, 0, stream>>>(pO, pl, out);
}